// Round 7
// baseline (221.590 us; speedup 1.0000x reference)
//
#include <hip/hip_runtime.h>
#include <hip/hip_bf16.h>
#include <cmath>

#define NN 4096    // H*W
typedef __attribute__((ext_vector_type(8))) short short8;
typedef __attribute__((ext_vector_type(4))) float f32x4;

__device__ __forceinline__ float bf2f(unsigned short u) {
  union { unsigned int i; float f; } c; c.i = ((unsigned int)u) << 16; return c.f;
}

// ---------------------------------------------------------------------------
// weight prep (proven): coalesced reads, scattered bf16 writes
// ---------------------------------------------------------------------------
__global__ __launch_bounds__(256) void cvt_w(
    const float* __restrict__ qkv_w, const float* __restrict__ off_w,
    const float* __restrict__ attw_w, const float* __restrict__ proj_w,
    __hip_bfloat16* __restrict__ wcatT, __hip_bfloat16* __restrict__ pjT)
{
  const int t = threadIdx.x;
  if (blockIdx.x < 256) {
    int k = blockIdx.x;
    wcatT[t * 256 + k] = __float2bfloat16(qkv_w[k * 768 + 512 + t]);
    if (t < 128) {
      int c2 = 256 + t;
      float v = 0.f;
      if (c2 < 320)      v = off_w[k * 64 + (c2 - 256)];
      else if (c2 < 352) v = attw_w[k * 32 + (c2 - 320)];
      wcatT[c2 * 256 + k] = __float2bfloat16(v);
    }
  } else {
    int k = blockIdx.x - 256;
    pjT[t * 256 + k] = __float2bfloat16(proj_w[k * 256 + t]);
  }
}

// ---------------------------------------------------------------------------
// fused v-GEMM + logits + table epilogue.
// R6: 32 rows x 384 cols, grid 1024 (4 blocks/CU), register-prefetch pipeline.
// 4 waves, each 32x96 (2x6 subtiles). LDS 33.3 KB.
// ---------------------------------------------------------------------------
__global__ __launch_bounds__(256) void gemm_voff(
    const float* __restrict__ x,
    const __hip_bfloat16* __restrict__ wcatT,
    const float* __restrict__ vbias,
    const float* __restrict__ off_b, const float* __restrict__ attw_b,
    __hip_bfloat16* __restrict__ vb,
    unsigned int* __restrict__ table)
{
  __shared__ float smemf[8320];               // 33280 B
  short* As = (short*)smemf;                  // 32*40 sh = 2560 B
  short* Bs = As + 32 * 40;                   // 384*40 sh = 30720 B
  float (*L)[100] = (float(*)[100])smemf;     // 32*100*4 = 12800 B (aliased after K loop)

  const int t = threadIdx.x;
  const int m0 = blockIdx.x * 32;
  const int wave = t >> 6, lane = t & 63, q = lane >> 4, ln = lane & 15;
  const int wn = wave * 96;

  f32x4 acc[2][6] = {};

  // staging tasks
  const int arow = t >> 3, akseg = t & 7;     // 32 rows x 8 k-segs of 4 floats
  const float* apg = x + (size_t)(m0 + arow) * 256 + akseg * 4;
  int brow[6], bseg[6];
#pragma unroll
  for (int i = 0; i < 6; ++i) { int u = t + i * 256; brow[i] = u >> 2; bseg[i] = u & 3; }

  // prefetch k0 = 0
  float4 a_pf = *(const float4*)(apg);
  int4 b_pf[6];
#pragma unroll
  for (int i = 0; i < 6; ++i)
    b_pf[i] = *(const int4*)&wcatT[(size_t)brow[i] * 256 + bseg[i] * 8];

  for (int k0 = 0; k0 < 256; k0 += 32) {
    // write prefetched tile to LDS
    alignas(8) __hip_bfloat16 cv[4] = {
      __float2bfloat16(a_pf.x), __float2bfloat16(a_pf.y),
      __float2bfloat16(a_pf.z), __float2bfloat16(a_pf.w)};
    *(int2*)&As[arow * 40 + akseg * 4] = *(int2*)cv;
#pragma unroll
    for (int i = 0; i < 6; ++i)
      *(int4*)&Bs[brow[i] * 40 + bseg[i] * 8] = b_pf[i];
    __syncthreads();
    // issue next iteration's loads (latency hides under ds_read+MFMA below)
    if (k0 < 224) {
      a_pf = *(const float4*)(apg + k0 + 32);
#pragma unroll
      for (int i = 0; i < 6; ++i)
        b_pf[i] = *(const int4*)&wcatT[(size_t)brow[i] * 256 + k0 + 32 + bseg[i] * 8];
    }
    short8 a[2], b[6];
#pragma unroll
    for (int i = 0; i < 2; ++i) a[i] = *(const short8*)&As[(i * 16 + ln) * 40 + q * 8];
#pragma unroll
    for (int j = 0; j < 6; ++j) b[j] = *(const short8*)&Bs[(wn + j * 16 + ln) * 40 + q * 8];
#pragma unroll
    for (int i = 0; i < 2; ++i)
#pragma unroll
      for (int j = 0; j < 6; ++j)
        acc[i][j] = __builtin_amdgcn_mfma_f32_16x16x32_bf16(a[i], b[j], acc[i][j], 0, 0, 0);
    __syncthreads();
  }

  // v outputs (global) + logits (LDS alias — safe after final barrier)
#pragma unroll
  for (int j = 0; j < 6; ++j) {
    int col = wn + j * 16 + ln;
    if (col < 256) {
      float bv = vbias[col];
#pragma unroll
      for (int i = 0; i < 2; ++i) {
        int rowb = m0 + i * 16 + q * 4;
#pragma unroll
        for (int r = 0; r < 4; ++r)
          vb[(size_t)(rowb + r) * 256 + col] = __float2bfloat16(acc[i][j][r] + bv);
      }
    } else if (col < 352) {
      int lc = col - 256;
      float bv = (lc < 64) ? off_b[lc] : attw_b[lc - 64];
#pragma unroll
      for (int i = 0; i < 2; ++i)
#pragma unroll
        for (int r = 0; r < 4; ++r)
          L[i * 16 + q * 4 + r][lc] = acc[i][j][r] + bv;
    }
  }
  __syncthreads();

  // table epilogue: 256 (row,head) pairs, exactly 1 per thread
  {
    int rr = t >> 3, h = t & 7;
    int row = m0 + rr;
    int nl = row & (NN - 1);
    float refx = (float)(nl & 63);
    float refy = (float)(nl >> 6);

    float a0 = L[rr][64 + h * 4 + 0], a1 = L[rr][64 + h * 4 + 1];
    float a2 = L[rr][64 + h * 4 + 2], a3 = L[rr][64 + h * 4 + 3];
    float mx = fmaxf(fmaxf(a0, a1), fmaxf(a2, a3));
    float e0 = expf(a0 - mx), e1 = expf(a1 - mx), e2 = expf(a2 - mx), e3 = expf(a3 - mx);
    float inv = 1.f / (e0 + e1 + e2 + e3);
    float at[4] = {e0 * inv, e1 * inv, e2 * inv, e3 * inv};

    alignas(16) unsigned short idxs[16];
    alignas(16) _Float16 wsv[16];
#pragma unroll
    for (int p = 0; p < 4; ++p) {
      float gx = refx + 2.f * tanhf(L[rr][h * 8 + p * 2 + 0]);
      float gy = refy + 2.f * tanhf(L[rr][h * 8 + p * 2 + 1]);
      float x0f = floorf(gx), y0f = floorf(gy);
      int x0 = (int)x0f, y0 = (int)y0f;
      int x1 = x0 + 1,   y1 = y0 + 1;
      float wx1 = gx - x0f, wx0 = 1.f - wx1;
      float wy1 = gy - y0f, wy0 = 1.f - wy1;
      int cx0 = min(max(x0, 0), 63), cx1 = min(max(x1, 0), 63);
      int cy0 = min(max(y0, 0), 63), cy1 = min(max(y1, 0), 63);
      float vx0 = (x0 >= 0 && x0 <= 63) ? 1.f : 0.f;
      float vx1 = (x1 >= 0 && x1 <= 63) ? 1.f : 0.f;
      float vy0 = (y0 >= 0 && y0 <= 63) ? 1.f : 0.f;
      float vy1 = (y1 >= 0 && y1 <= 63) ? 1.f : 0.f;
      float ap = at[p];
      idxs[p * 4 + 0] = (unsigned short)(cy0 * 64 + cx0);
      idxs[p * 4 + 1] = (unsigned short)(cy0 * 64 + cx1);
      idxs[p * 4 + 2] = (unsigned short)(cy1 * 64 + cx0);
      idxs[p * 4 + 3] = (unsigned short)(cy1 * 64 + cx1);
      wsv[p * 4 + 0] = (_Float16)(ap * wx0 * wy0 * vx0 * vy0);
      wsv[p * 4 + 1] = (_Float16)(ap * wx1 * wy0 * vx1 * vy0);
      wsv[p * 4 + 2] = (_Float16)(ap * wx0 * wy1 * vx0 * vy1);
      wsv[p * 4 + 3] = (_Float16)(ap * wx1 * wy1 * vx1 * vy1);
    }
    uint4* dst = (uint4*)(table + ((size_t)row * 8 + h) * 16);  // pair-major
    dst[0] = *(uint4*)&idxs[0];
    dst[1] = *(uint4*)&idxs[8];
    dst[2] = *(uint4*)&wsv[0];
    dst[3] = *(uint4*)&wsv[8];
  }
}

// ---------------------------------------------------------------------------
// fused sampler + proj. R6: 32 rows x 256 cols, grid 1024 (4 blocks/CU).
// Phase 1: gather 32x256 y-tile into LDS (1024 tasks = 4/thread, high MLP).
// Phase 2: 8-step MFMA K-loop vs pjT with register-prefetch of Bs.
// ---------------------------------------------------------------------------
__global__ __launch_bounds__(256) void gemm_sproj(
    const __hip_bfloat16* __restrict__ vb,
    const unsigned int* __restrict__ table,
    const __hip_bfloat16* __restrict__ pjT,
    const float* __restrict__ bias,
    float* __restrict__ out)
{
  __shared__ short ytile[32 * 264];   // 16896 B (stride 132 words -> 2-way max)
  __shared__ short Bs[256 * 40];      // 20480 B
  const int t = threadIdx.x;
  const int m0 = blockIdx.x * 32;
  const int wave = t >> 6, lane = t & 63, q = lane >> 4, ln = lane & 15;
  const int wn = wave * 64;
  const int b = m0 >> 12;

  // ---- phase 1: gather y-tile (32 rows x 8 heads x 4 ch-groups)
#pragma unroll
  for (int i = 0; i < 4; ++i) {
    int tau = t + i * 256;
    int r = tau >> 5, h = (tau >> 2) & 7, g = tau & 3;
    int row = m0 + r;
    const uint4* tp = (const uint4*)(table + ((size_t)row * 8 + h) * 16);
    uint4 e0 = tp[0], e1 = tp[1];
    uint4 e2 = tp[2], e3 = tp[3];
    const unsigned int iw[8] = {e0.x, e0.y, e0.z, e0.w, e1.x, e1.y, e1.z, e1.w};
    const unsigned int ww[8] = {e2.x, e2.y, e2.z, e2.w, e3.x, e3.y, e3.z, e3.w};
    const char* vbase = (const char*)(vb + ((size_t)b * NN * 256) + h * 32 + g * 8);
    float accg[8] = {};
#pragma unroll
    for (int j = 0; j < 16; ++j) {
      unsigned int idx = (iw[j >> 1] >> ((j & 1) * 16)) & 0xffffu;
      union { unsigned int u; _Float16 h2[2]; } wu; wu.u = ww[j >> 1];
      float w = (float)wu.h2[j & 1];
      int4 pk = *(const int4*)(vbase + (size_t)idx * 512);
      const unsigned short* uu = (const unsigned short*)&pk;
#pragma unroll
      for (int c = 0; c < 8; ++c) accg[c] += w * bf2f(uu[c]);
    }
    alignas(16) __hip_bfloat16 o[8];
#pragma unroll
    for (int c = 0; c < 8; ++c) o[c] = __float2bfloat16(accg[c]);
    *(int4*)&ytile[r * 264 + h * 32 + g * 8] = *(int4*)o;
  }

  // ---- phase 2: MFMA K-loop with Bs register-prefetch
  int brow[4], bseg[4];
#pragma unroll
  for (int i = 0; i < 4; ++i) { int u = t + i * 256; brow[i] = u >> 2; bseg[i] = u & 3; }
  int4 b_pf[4];
#pragma unroll
  for (int i = 0; i < 4; ++i)
    b_pf[i] = *(const int4*)&pjT[(size_t)brow[i] * 256 + bseg[i] * 8];

  f32x4 acc[2][4] = {};
  for (int k0 = 0; k0 < 256; k0 += 32) {
#pragma unroll
    for (int i = 0; i < 4; ++i)
      *(int4*)&Bs[brow[i] * 40 + bseg[i] * 8] = b_pf[i];
    __syncthreads();                 // first iter: also publishes ytile
    if (k0 < 224) {
#pragma unroll
      for (int i = 0; i < 4; ++i)
        b_pf[i] = *(const int4*)&pjT[(size_t)brow[i] * 256 + k0 + 32 + bseg[i] * 8];
    }
    short8 a[2], bfr[4];
#pragma unroll
    for (int i = 0; i < 2; ++i) a[i] = *(const short8*)&ytile[(i * 16 + ln) * 264 + k0 + q * 8];
#pragma unroll
    for (int j = 0; j < 4; ++j) bfr[j] = *(const short8*)&Bs[(wn + j * 16 + ln) * 40 + q * 8];
#pragma unroll
    for (int i = 0; i < 2; ++i)
#pragma unroll
      for (int j = 0; j < 4; ++j)
        acc[i][j] = __builtin_amdgcn_mfma_f32_16x16x32_bf16(a[i], bfr[j], acc[i][j], 0, 0, 0);
    __syncthreads();
  }

#pragma unroll
  for (int j = 0; j < 4; ++j) {
    int col = wn + j * 16 + ln;
    float bv = bias[col];
#pragma unroll
    for (int i = 0; i < 2; ++i) {
      int rowb = m0 + i * 16 + q * 4;
#pragma unroll
      for (int r = 0; r < 4; ++r)
        out[(size_t)(rowb + r) * 256 + col] = acc[i][j][r] + bv;
    }
  }
}

// ---------------------------------------------------------------------------
extern "C" void kernel_launch(void* const* d_in, const int* in_sizes, int n_in,
                              void* d_out, int out_size, void* d_ws, size_t ws_size,
                              hipStream_t stream) {
  const float* x      = (const float*)d_in[0];
  const float* qkv_w  = (const float*)d_in[1];
  const float* qkv_b  = (const float*)d_in[2];
  const float* off_w  = (const float*)d_in[3];
  const float* off_b  = (const float*)d_in[4];
  const float* attw_w = (const float*)d_in[5];
  const float* attw_b = (const float*)d_in[6];
  const float* proj_w = (const float*)d_in[7];
  const float* proj_b = (const float*)d_in[8];
  float* out = (float*)d_out;

  char* ws = (char*)d_ws;
  __hip_bfloat16* vb    = (__hip_bfloat16*)(ws);                 // 16 MiB
  unsigned int*   table = (unsigned int*)  (ws + 16777216);      // 16 MiB
  __hip_bfloat16* wcatT = (__hip_bfloat16*)(ws + 33554432);      // 192 KiB
  __hip_bfloat16* pjT   = (__hip_bfloat16*)(ws + 33751040);      // 128 KiB

  cvt_w<<<512, 256, 0, stream>>>(qkv_w, off_w, attw_w, proj_w, wcatT, pjT);
  gemm_voff<<<1024, 256, 0, stream>>>(x, wcatT, qkv_b + 512, off_b, attw_b, vb, table);
  gemm_sproj<<<1024, 256, 0, stream>>>(vb, table, pjT, proj_b, out);
}

// Round 8
// 160.405 us; speedup vs baseline: 1.3814x; 1.3814x over previous
//
#include <hip/hip_runtime.h>
#include <hip/hip_bf16.h>
#include <cmath>

#define NN 4096    // H*W
typedef __attribute__((ext_vector_type(8))) short short8;
typedef __attribute__((ext_vector_type(4))) float f32x4;

__device__ __forceinline__ float bf2f(unsigned short u) {
  union { unsigned int i; float f; } c; c.i = ((unsigned int)u) << 16; return c.f;
}

// ---------------------------------------------------------------------------
// weight prep v2: LDS-transpose, coalesced reads AND coalesced full-line writes.
// 40 blocks x 256 thr. Tiles 0..23: wcatT (6 c-tiles x 4 k-tiles);
// tiles 24..39: pjT (4 x 4). Each tile: 64 c x 64 k.
//   wcatT[c][k]: c<256 qkv_w[k][512+c]; c<320 off_w[k][c-256];
//                c<352 attw_w[k][c-320]; else 0.   pjT[c][k]=proj_w[k][c].
// ---------------------------------------------------------------------------
__global__ __launch_bounds__(256) void cvt_w(
    const float* __restrict__ qkv_w, const float* __restrict__ off_w,
    const float* __restrict__ attw_w, const float* __restrict__ proj_w,
    __hip_bfloat16* __restrict__ wcatT, __hip_bfloat16* __restrict__ pjT)
{
  __shared__ short T[64][72];           // T[c][k], row pad 72 (2-way max on write)
  const int t = threadIdx.x;
  const int tile = blockIdx.x;
  const bool isP = tile >= 24;
  const int ct = isP ? (tile - 24) & 3 : tile % 6;
  const int kt = isP ? (tile - 24) >> 2 : tile / 6;
  const int c0 = ct * 64, k0 = kt * 64;

  // read phase: 4 rows per thread; row kk = r*16 + (t>>4), cols cc = (t&15)*4
#pragma unroll
  for (int r = 0; r < 4; ++r) {
    int kk = r * 16 + (t >> 4);
    int cc = (t & 15) * 4;
    int k = k0 + kk, gc = c0 + cc;
    float4 v;
    if (isP) {
      v = *(const float4*)&proj_w[(size_t)k * 256 + gc];
    } else if (gc < 256) {
      v = *(const float4*)&qkv_w[(size_t)k * 768 + 512 + gc];
    } else if (gc < 320) {
      v = *(const float4*)&off_w[(size_t)k * 64 + (gc - 256)];
    } else if (gc < 352) {
      v = *(const float4*)&attw_w[(size_t)k * 32 + (gc - 320)];
    } else {
      v = make_float4(0.f, 0.f, 0.f, 0.f);
    }
    T[cc + 0][kk] = ((__hip_bfloat16_raw)__float2bfloat16(v.x)).x;
    T[cc + 1][kk] = ((__hip_bfloat16_raw)__float2bfloat16(v.y)).x;
    T[cc + 2][kk] = ((__hip_bfloat16_raw)__float2bfloat16(v.z)).x;
    T[cc + 3][kk] = ((__hip_bfloat16_raw)__float2bfloat16(v.w)).x;
  }
  __syncthreads();

  // write phase: thread -> c = t>>2, kseg = t&3 (16 shorts = 2 int4), contiguous k
  {
    int c = t >> 2, kseg = t & 3;
    __hip_bfloat16* dst = (isP ? pjT : wcatT) + (size_t)(c0 + c) * 256 + k0 + kseg * 16;
    *(int4*)(dst)     = *(int4*)&T[c][kseg * 16];
    *(int4*)(dst + 8) = *(int4*)&T[c][kseg * 16 + 8];
  }
}

// ---------------------------------------------------------------------------
// fused v-GEMM + offset/attention logits + sampling-table epilogue (R4 exact).
// 512 threads (8 waves, 2x4), tile 128 rows x 384 cols, x read exactly once.
// table pair-major: entry (row*8+h) = 16 ushort idx (32B) + 16 fp16 w (32B).
// ---------------------------------------------------------------------------
__global__ __launch_bounds__(512) void gemm_voff(
    const float* __restrict__ x,
    const __hip_bfloat16* __restrict__ wcatT,
    const float* __restrict__ vbias,
    const float* __restrict__ off_b, const float* __restrict__ attw_b,
    __hip_bfloat16* __restrict__ vb,
    unsigned int* __restrict__ table)
{
  __shared__ float smemf[12800];              // 51200 B
  short* As = (short*)smemf;                  // 128 * 40 shorts = 10240 B
  short* Bs = As + 128 * 40;                  // 384 * 40 shorts = 30720 B
  float (*L)[100] = (float(*)[100])smemf;     // aliased AFTER the K loop

  const int t = threadIdx.x;
  const int m0 = blockIdx.x * 128;
  const int wave = t >> 6, lane = t & 63, q = lane >> 4, ln = lane & 15;
  const int wm = (wave & 1) * 64, wn = (wave >> 1) * 96;

  f32x4 acc[4][6] = {};

  const int arow = t >> 2, aseg = t & 3;          // A staging: 128 rows x 4 segs
  const float* apg = x + (size_t)(m0 + arow) * 256 + aseg * 8;

  for (int k0 = 0; k0 < 256; k0 += 32) {
    // A: 128x32 fp32 -> bf16
    float4 f0 = *(const float4*)(apg + k0);
    float4 f1 = *(const float4*)(apg + k0 + 4);
    alignas(16) __hip_bfloat16 cv[8] = {
      __float2bfloat16(f0.x), __float2bfloat16(f0.y), __float2bfloat16(f0.z), __float2bfloat16(f0.w),
      __float2bfloat16(f1.x), __float2bfloat16(f1.y), __float2bfloat16(f1.z), __float2bfloat16(f1.w)};
    *(int4*)&As[arow * 40 + aseg * 8] = *(int4*)cv;
    // B: 384x32 bf16, 1536 16B units / 512 thr = 3 each
#pragma unroll
    for (int i = 0; i < 3; ++i) {
      int u = t + i * 512;
      int brow = u >> 2, bseg = u & 3;
      *(int4*)&Bs[brow * 40 + bseg * 8] =
          *(const int4*)&wcatT[(size_t)brow * 256 + k0 + bseg * 8];
    }
    __syncthreads();
    short8 a[4], b[6];
#pragma unroll
    for (int i = 0; i < 4; ++i) a[i] = *(const short8*)&As[(wm + i * 16 + ln) * 40 + q * 8];
#pragma unroll
    for (int j = 0; j < 6; ++j) b[j] = *(const short8*)&Bs[(wn + j * 16 + ln) * 40 + q * 8];
#pragma unroll
    for (int i = 0; i < 4; ++i)
#pragma unroll
      for (int j = 0; j < 6; ++j)
        acc[i][j] = __builtin_amdgcn_mfma_f32_16x16x32_bf16(a[i], b[j], acc[i][j], 0, 0, 0);
    __syncthreads();
  }

  // v outputs + logits to LDS
#pragma unroll
  for (int j = 0; j < 6; ++j) {
    int col = wn + j * 16 + ln;
    if (col < 256) {
      float bv = vbias[col];
#pragma unroll
      for (int i = 0; i < 4; ++i) {
        int rowb = m0 + wm + i * 16 + q * 4;
#pragma unroll
        for (int r = 0; r < 4; ++r)
          vb[(size_t)(rowb + r) * 256 + col] = __float2bfloat16(acc[i][j][r] + bv);
      }
    } else if (col < 352) {
      int lc = col - 256;
      float bv = (lc < 64) ? off_b[lc] : attw_b[lc - 64];
#pragma unroll
      for (int i = 0; i < 4; ++i)
#pragma unroll
        for (int r = 0; r < 4; ++r)
          L[wm + i * 16 + q * 4 + r][lc] = acc[i][j][r] + bv;
    }
  }
  __syncthreads();

  // table epilogue: 1024 (row,head) pairs, 2 per thread
#pragma unroll
  for (int it = 0; it < 2; ++it) {
    int pl = t + it * 512;
    int rr = pl >> 3, h = pl & 7;
    int row = m0 + rr;
    int nl = row & (NN - 1);
    float refx = (float)(nl & 63);
    float refy = (float)(nl >> 6);

    float a0 = L[rr][64 + h * 4 + 0], a1 = L[rr][64 + h * 4 + 1];
    float a2 = L[rr][64 + h * 4 + 2], a3 = L[rr][64 + h * 4 + 3];
    float mx = fmaxf(fmaxf(a0, a1), fmaxf(a2, a3));
    float e0 = expf(a0 - mx), e1 = expf(a1 - mx), e2 = expf(a2 - mx), e3 = expf(a3 - mx);
    float inv = 1.f / (e0 + e1 + e2 + e3);
    float at[4] = {e0 * inv, e1 * inv, e2 * inv, e3 * inv};

    alignas(16) unsigned short idxs[16];
    alignas(16) _Float16 wsv[16];
#pragma unroll
    for (int p = 0; p < 4; ++p) {
      float gx = refx + 2.f * tanhf(L[rr][h * 8 + p * 2 + 0]);
      float gy = refy + 2.f * tanhf(L[rr][h * 8 + p * 2 + 1]);
      float x0f = floorf(gx), y0f = floorf(gy);
      int x0 = (int)x0f, y0 = (int)y0f;
      int x1 = x0 + 1,   y1 = y0 + 1;
      float wx1 = gx - x0f, wx0 = 1.f - wx1;
      float wy1 = gy - y0f, wy0 = 1.f - wy1;
      int cx0 = min(max(x0, 0), 63), cx1 = min(max(x1, 0), 63);
      int cy0 = min(max(y0, 0), 63), cy1 = min(max(y1, 0), 63);
      float vx0 = (x0 >= 0 && x0 <= 63) ? 1.f : 0.f;
      float vx1 = (x1 >= 0 && x1 <= 63) ? 1.f : 0.f;
      float vy0 = (y0 >= 0 && y0 <= 63) ? 1.f : 0.f;
      float vy1 = (y1 >= 0 && y1 <= 63) ? 1.f : 0.f;
      float ap = at[p];
      idxs[p * 4 + 0] = (unsigned short)(cy0 * 64 + cx0);
      idxs[p * 4 + 1] = (unsigned short)(cy0 * 64 + cx1);
      idxs[p * 4 + 2] = (unsigned short)(cy1 * 64 + cx0);
      idxs[p * 4 + 3] = (unsigned short)(cy1 * 64 + cx1);
      wsv[p * 4 + 0] = (_Float16)(ap * wx0 * wy0 * vx0 * vy0);
      wsv[p * 4 + 1] = (_Float16)(ap * wx1 * wy0 * vx1 * vy0);
      wsv[p * 4 + 2] = (_Float16)(ap * wx0 * wy1 * vx0 * vy1);
      wsv[p * 4 + 3] = (_Float16)(ap * wx1 * wy1 * vx1 * vy1);
    }
    uint4* dst = (uint4*)(table + ((size_t)row * 8 + h) * 16);  // pair-major
    dst[0] = *(uint4*)&idxs[0];
    dst[1] = *(uint4*)&idxs[8];
    dst[2] = *(uint4*)&wsv[0];
    dst[3] = *(uint4*)&wsv[8];
  }
}

// ---------------------------------------------------------------------------
// fused sampler + proj (R5 exact). Per block: 64-row out tile, ALL 256 cols.
// Phase 1: gather the full 64x256 y-tile into LDS. Phase 2: 8-step MFMA
// K-loop vs pjT (y-tile static in LDS). 4 waves, wave tile 64x64. Grid 512.
// ---------------------------------------------------------------------------
__global__ __launch_bounds__(256) void gemm_sproj(
    const __hip_bfloat16* __restrict__ vb,
    const unsigned int* __restrict__ table,
    const __hip_bfloat16* __restrict__ pjT,
    const float* __restrict__ bias,
    float* __restrict__ out)
{
  __shared__ short ytile[64 * 264];   // 33792 B (row stride 264 -> 2-way max)
  __shared__ short Bs[256 * 40];      // 20480 B
  const int t = threadIdx.x;
  const int m0 = blockIdx.x * 64;
  const int wave = t >> 6, lane = t & 63, q = lane >> 4, ln = lane & 15;
  const int wn = wave * 64;
  const int b = m0 >> 12;             // whole block in one batch (4096%64==0)

  // ---- phase 1: gather y-tile (2048 tasks = 64 rows x 8 heads x 4 ch-groups)
#pragma unroll
  for (int i = 0; i < 8; ++i) {
    int tau = t + i * 256;
    int r = tau >> 5, h = (tau >> 2) & 7, g = tau & 3;
    int row = m0 + r;
    const uint4* tp = (const uint4*)(table + ((size_t)row * 8 + h) * 16);
    uint4 e0 = tp[0], e1 = tp[1];     // 16 ushort idx
    uint4 e2 = tp[2], e3 = tp[3];     // 16 fp16 weights
    const unsigned int iw[8] = {e0.x, e0.y, e0.z, e0.w, e1.x, e1.y, e1.z, e1.w};
    const unsigned int ww[8] = {e2.x, e2.y, e2.z, e2.w, e3.x, e3.y, e3.z, e3.w};
    const char* vbase = (const char*)(vb + ((size_t)b * NN * 256) + h * 32 + g * 8);
    float accg[8] = {};
#pragma unroll
    for (int j = 0; j < 16; ++j) {
      unsigned int idx = (iw[j >> 1] >> ((j & 1) * 16)) & 0xffffu;
      union { unsigned int u; _Float16 h2[2]; } wu; wu.u = ww[j >> 1];
      float w = (float)wu.h2[j & 1];
      int4 pk = *(const int4*)(vbase + (size_t)idx * 512);
      const unsigned short* uu = (const unsigned short*)&pk;
#pragma unroll
      for (int c = 0; c < 8; ++c) accg[c] += w * bf2f(uu[c]);
    }
    alignas(16) __hip_bfloat16 o[8];
#pragma unroll
    for (int c = 0; c < 8; ++c) o[c] = __float2bfloat16(accg[c]);
    *(int4*)&ytile[r * 264 + h * 32 + g * 8] = *(int4*)o;
  }
  __syncthreads();

  // ---- phase 2: MFMA K-loop (y-tile static; only Bs double-barriered)
  f32x4 acc[4][4] = {};
  for (int k0 = 0; k0 < 256; k0 += 32) {
#pragma unroll
    for (int i = 0; i < 4; ++i) {
      int u = t + i * 256;
      int brow = u >> 2, bseg = u & 3;
      *(int4*)&Bs[brow * 40 + bseg * 8] =
          *(const int4*)&pjT[(size_t)brow * 256 + k0 + bseg * 8];
    }
    __syncthreads();
    short8 a[4], bfr[4];
#pragma unroll
    for (int i = 0; i < 4; ++i) a[i] = *(const short8*)&ytile[(i * 16 + ln) * 264 + k0 + q * 8];
#pragma unroll
    for (int j = 0; j < 4; ++j) bfr[j] = *(const short8*)&Bs[(wn + j * 16 + ln) * 40 + q * 8];
#pragma unroll
    for (int i = 0; i < 4; ++i)
#pragma unroll
      for (int j = 0; j < 4; ++j)
        acc[i][j] = __builtin_amdgcn_mfma_f32_16x16x32_bf16(a[i], bfr[j], acc[i][j], 0, 0, 0);
    __syncthreads();
  }

#pragma unroll
  for (int j = 0; j < 4; ++j) {
    int col = wn + j * 16 + ln;
    float bv = bias[col];
#pragma unroll
    for (int i = 0; i < 4; ++i) {
      int rowb = m0 + i * 16 + q * 4;
#pragma unroll
      for (int r = 0; r < 4; ++r)
        out[(size_t)(rowb + r) * 256 + col] = acc[i][j][r] + bv;
    }
  }
}

// ---------------------------------------------------------------------------
extern "C" void kernel_launch(void* const* d_in, const int* in_sizes, int n_in,
                              void* d_out, int out_size, void* d_ws, size_t ws_size,
                              hipStream_t stream) {
  const float* x      = (const float*)d_in[0];
  const float* qkv_w  = (const float*)d_in[1];
  const float* qkv_b  = (const float*)d_in[2];
  const float* off_w  = (const float*)d_in[3];
  const float* off_b  = (const float*)d_in[4];
  const float* attw_w = (const float*)d_in[5];
  const float* attw_b = (const float*)d_in[6];
  const float* proj_w = (const float*)d_in[7];
  const float* proj_b = (const float*)d_in[8];
  float* out = (float*)d_out;

  char* ws = (char*)d_ws;
  __hip_bfloat16* vb    = (__hip_bfloat16*)(ws);                 // 16 MiB
  unsigned int*   table = (unsigned int*)  (ws + 16777216);      // 16 MiB
  __hip_bfloat16* wcatT = (__hip_bfloat16*)(ws + 33554432);      // 192 KiB
  __hip_bfloat16* pjT   = (__hip_bfloat16*)(ws + 33751040);      // 128 KiB

  cvt_w<<<40, 256, 0, stream>>>(qkv_w, off_w, attw_w, proj_w, wcatT, pjT);
  gemm_voff<<<256, 512, 0, stream>>>(x, wcatT, qkv_b + 512, off_b, attw_b, vb, table);
  gemm_sproj<<<512, 256, 0, stream>>>(vb, table, pjT, proj_b, out);
}